// Round 9
// baseline (746.006 us; speedup 1.0000x reference)
//
#include <hip/hip_runtime.h>
#include <stdint.h>

#define DEVI __device__ __forceinline__

typedef __attribute__((ext_vector_type(8))) short bf16x8;   // MFMA A/B frag (8 bf16)
typedef __attribute__((ext_vector_type(4))) float f32x4;    // 16x16 MFMA C/D frag
typedef __attribute__((ext_vector_type(4))) int int4v;

DEVI unsigned short f2bf(float f) {  // fp32 -> bf16, round-to-nearest-even
  union { float f; unsigned u; } v; v.f = f;
  return (unsigned short)((v.u + 0x7FFFu + ((v.u >> 16) & 1u)) >> 16);
}

DEVI void gll16(const void* g, void* l) {  // global -> LDS direct, 16B/lane
  __builtin_amdgcn_global_load_lds((__attribute__((address_space(1))) void*)g,
                                   (__attribute__((address_space(3))) void*)l, 16, 0, 0);
}

// ---------------- fp32 -> bf16 conversion (weights) ----------------
__global__ __launch_bounds__(256) void cvt_kernel(const float* __restrict__ s,
                                                  unsigned short* __restrict__ d, int n) {
  int i = (blockIdx.x * 256 + threadIdx.x) * 4;
  if (i >= n) return;
  float4 v = *(const float4*)(s + i);
  union { unsigned short u[4]; uint2 w; } o;
  o.u[0] = f2bf(v.x); o.u[1] = f2bf(v.y); o.u[2] = f2bf(v.z); o.u[3] = f2bf(v.w);
  *(uint2*)(d + i) = o.w;
}

// ---------------- GEMM: C[M=8192,N=1024] = A @ B^T + bias ----------------
// A: reg-staged (fp32->bf16 fused, or bf16 copy) into PADDED LDS (round-1 verified).
// B: global_load_lds 16B into LINEAR [128][64] LDS  <-- the gll16 A/B test.
// OUT_MODE 0: fp32 row-major (val*oscale)
// OUT_MODE 1: bf16 heads [bh][s][64]
// OUT_MODE 2: bf16 headsT [bh][d][s]  (V^T for attention)
template<bool A_F32, int OUT_MODE>
__global__ __launch_bounds__(256) void gemm_bt(const void* __restrict__ Aptr,
                                               const unsigned short* __restrict__ Bmat,
                                               const float* __restrict__ bias,
                                               void* __restrict__ Cptr, float oscale) {
  constexpr int K = 1024;
  constexpr int LDT = 72;  // A pad 64->72 (round-1 verified)
  __shared__ __align__(16) unsigned short Alds[128][LDT];
  __shared__ __align__(16) unsigned short Bl[128][64];   // linear: gll16 dest
  const int tid = threadIdx.x;
  const int lane = tid & 63, w = tid >> 6;
  const int wm = w >> 1, wn = w & 1;
  const int l15 = lane & 15, lq = lane >> 4;
  const int rowBase = blockIdx.x * 128, colBase = blockIdx.y * 128;
  const int arow = tid >> 1, acol = (tid & 1) * 32;

  f32x4 acc[4][4] = {};

  float4 afp[8]; int4v abf[4];
  auto loadA = [&](int k0) {
    if (A_F32) {
      const float* p = (const float*)Aptr + (size_t)(rowBase + arow) * K + k0 + acol;
#pragma unroll
      for (int i = 0; i < 8; i++) afp[i] = *(const float4*)(p + i * 4);
    } else {
      const unsigned short* p = (const unsigned short*)Aptr + (size_t)(rowBase + arow) * K + k0 + acol;
#pragma unroll
      for (int i = 0; i < 4; i++) abf[i] = *(const int4v*)(p + i * 8);
    }
  };
  loadA(0);

  for (int k0 = 0; k0 < K; k0 += 64) {
    __syncthreads();                  // prev compute done -> Alds/Bl free
    // B: issue 16B/lane direct-to-LDS (lane L -> Bl row +L>>3, col (L&7)*8; matches src)
#pragma unroll
    for (int i = 0; i < 4; i++) {
      int r = w * 32 + i * 8 + (lane >> 3);
      gll16(Bmat + (size_t)(colBase + r) * 1024 + k0 + (lane & 7) * 8, &Bl[w * 32 + i * 8][0]);
    }
    // A: cvt + store (VALU work covers part of B's L2 latency)
    if (A_F32) {
      unsigned short t[32];
#pragma unroll
      for (int i = 0; i < 8; i++) {
        t[i*4+0] = f2bf(afp[i].x); t[i*4+1] = f2bf(afp[i].y);
        t[i*4+2] = f2bf(afp[i].z); t[i*4+3] = f2bf(afp[i].w);
      }
#pragma unroll
      for (int i = 0; i < 4; i++) *(int4v*)&Alds[arow][acol + i*8] = *(const int4v*)&t[i*8];
    } else {
#pragma unroll
      for (int i = 0; i < 4; i++) *(int4v*)&Alds[arow][acol + i*8] = abf[i];
    }
    if (k0 + 64 < K) loadA(k0 + 64);  // prefetch next A into regs
    __syncthreads();                  // drains vmcnt (gll16) + lgkm (A writes)
#pragma unroll
    for (int kc = 0; kc < 2; kc++) {
      bf16x8 af[4], bfr[4];
#pragma unroll
      for (int m = 0; m < 4; m++)
        af[m] = *(const bf16x8*)&Alds[wm*64 + m*16 + l15][kc*32 + lq*8];
#pragma unroll
      for (int n = 0; n < 4; n++)
        bfr[n] = *(const bf16x8*)&Bl[wn*64 + n*16 + l15][kc*32 + lq*8];
#pragma unroll
      for (int m = 0; m < 4; m++)
#pragma unroll
        for (int n = 0; n < 4; n++)
          acc[m][n] = __builtin_amdgcn_mfma_f32_16x16x32_bf16(af[m], bfr[n], acc[m][n], 0, 0, 0);
    }
  }
  // epilogue: verified C/D layout col=lane&15, row=(lane>>4)*4+reg
#pragma unroll
  for (int n = 0; n < 4; n++) {
    int col = colBase + wn*64 + n*16 + l15;
    float bv = bias[col];
#pragma unroll
    for (int m = 0; m < 4; m++) {
      int row0 = rowBase + wm*64 + m*16 + lq*4;
#pragma unroll
      for (int r = 0; r < 4; r++) {
        int row = row0 + r;
        float val = (acc[m][n][r] + bv) * oscale;
        if (OUT_MODE == 0) {
          ((float*)Cptr)[(size_t)row * 1024 + col] = val;
        } else {
          unsigned short* C = (unsigned short*)Cptr;
          int hh = col >> 6, dd = col & 63;
          int bb = row >> 11, ss = row & 2047;
          int bh = bb * 16 + hh;
          if (OUT_MODE == 1) C[(((size_t)bh * 2048 + ss) << 6) + dd] = f2bf(val);
          else               C[((size_t)bh << 17) + ((size_t)dd << 11) + ss] = f2bf(val);
        }
      }
    }
  }
}

// ---------------- flash attention: swapped QK^T, 16x16x32 MFMAs ONLY ----------------
// Body identical to round-8 PASS; re-gridded to 1 wave per block (64 thr x 4096 blocks)
// for occupancy: kernel has zero LDS / zero barriers, so blocks gained nothing.
// S^T = mfma(K, Q^T): C col = q = l15, row = key(within 16-blk) = lq*4 + reg.
// Softmax in-register, exp2-space (Q pre-scaled by 0.125*log2e), defer-max THR=11.5.
__global__ __launch_bounds__(64, 4) void attn_kernel(const unsigned short* __restrict__ Qh,
                                                     const unsigned short* __restrict__ Kh,
                                                     const unsigned short* __restrict__ VT,
                                                     unsigned short* __restrict__ Ob) {
  const int lane = threadIdx.x & 63;
  const int l15 = lane & 15, lq = lane >> 4;
  // XCD-chunked swizzle (4096 % 8 == 0, bijective): 8 bh (4MB K+V) per XCD L2
  const int bid = blockIdx.x;
  const int xcd = bid & 7, slot = bid >> 3;          // 512 slots per XCD
  const int bh = xcd * 8 + (slot >> 6), qs = slot & 63;
  const int qbase = qs * 32;
  const unsigned short* Qp = Qh + ((size_t)bh << 17);
  const unsigned short* Kp = Kh + ((size_t)bh << 17);
  const unsigned short* Vp = VT + ((size_t)bh << 17);

  // Q B-frags: col=q=l15, k = kc*32 + lq*8 + j (verified round-0 convention)
  bf16x8 qb[2][2];
#pragma unroll
  for (int mi = 0; mi < 2; mi++)
#pragma unroll
    for (int kc = 0; kc < 2; kc++)
      qb[mi][kc] = *(const bf16x8*)(Qp + (size_t)(qbase + mi*16 + l15) * 64 + kc*32 + lq*8);

  f32x4 oacc[2][4] = {};                    // O^T: col=q=l15, row d = 16*db + 4*lq + reg
  float mrun[2] = {-1e30f, -1e30f};
  float lrun[2] = {0.f, 0.f};

  bf16x8 kaA[4][2], kaB[4][2];              // K A-frags, double-buffered
  auto loadK = [&](bf16x8 (&ka)[4][2], int kt) {
#pragma unroll
    for (int kb = 0; kb < 4; kb++)
#pragma unroll
      for (int kc = 0; kc < 2; kc++)
        ka[kb][kc] = *(const bf16x8*)(Kp + (size_t)(kt + kb*16 + l15) * 64 + kc*32 + lq*8);
  };
  loadK(kaA, 0);

  auto tile = [&](bf16x8 (&ka)[4][2], bf16x8 (&kan)[4][2], int kt, int ktn) {
    // V^T A-frags: row d = db*16 + l15, k = key = win*32 + lq*8 + j
    bf16x8 va[4][2];
#pragma unroll
    for (int db = 0; db < 4; db++)
#pragma unroll
      for (int win = 0; win < 2; win++)
        va[db][win] = *(const bf16x8*)(Vp + (size_t)(db*16 + l15) * 2048 + kt + win*32 + lq*8);

    // QK^T: sf[mi][kb][r] = score(q = qbase+16mi+l15, key = kt+16kb+4lq+r), log2-scaled
    f32x4 sf[2][4] = {};
#pragma unroll
    for (int kc = 0; kc < 2; kc++)
#pragma unroll
      for (int mi = 0; mi < 2; mi++)
#pragma unroll
        for (int kb = 0; kb < 4; kb++)
          sf[mi][kb] = __builtin_amdgcn_mfma_f32_16x16x32_bf16(ka[kb][kc], qb[mi][kc], sf[mi][kb], 0, 0, 0);

    if (ktn < 2048) loadK(kan, ktn);       // prefetch next K under softmax

    // ---- online softmax: local 16-tree + shfl_xor{16,32} across the 4 lq-groups
    float pm[2];
#pragma unroll
    for (int mi = 0; mi < 2; mi++) {
      float t0 = fmaxf(fmaxf(sf[mi][0][0], sf[mi][0][1]), fmaxf(sf[mi][0][2], sf[mi][0][3]));
      float t1 = fmaxf(fmaxf(sf[mi][1][0], sf[mi][1][1]), fmaxf(sf[mi][1][2], sf[mi][1][3]));
      float t2 = fmaxf(fmaxf(sf[mi][2][0], sf[mi][2][1]), fmaxf(sf[mi][2][2], sf[mi][2][3]));
      float t3 = fmaxf(fmaxf(sf[mi][3][0], sf[mi][3][1]), fmaxf(sf[mi][3][2], sf[mi][3][3]));
      float t = fmaxf(fmaxf(t0, t1), fmaxf(t2, t3));
      t = fmaxf(t, __shfl_xor(t, 16));
      t = fmaxf(t, __shfl_xor(t, 32));
      pm[mi] = t;
    }
    if (__any((pm[0] > mrun[0] + 11.5f) || (pm[1] > mrun[1] + 11.5f))) {  // defer-max
#pragma unroll
      for (int mi = 0; mi < 2; mi++) {
        float mnew = fmaxf(mrun[mi], pm[mi]);
        float alpha = __builtin_amdgcn_exp2f(mrun[mi] - mnew);
        mrun[mi] = mnew; lrun[mi] *= alpha;
#pragma unroll
        for (int db = 0; db < 4; db++)
#pragma unroll
          for (int r = 0; r < 4; r++) oacc[mi][db][r] *= alpha;
      }
    }
#pragma unroll
    for (int mi = 0; mi < 2; mi++) {
      float s = 0.f;
#pragma unroll
      for (int kb = 0; kb < 4; kb++)
#pragma unroll
        for (int r = 0; r < 4; r++) {
          float e = __builtin_amdgcn_exp2f(sf[mi][kb][r] - mrun[mi]);
          sf[mi][kb][r] = e; s += e;
        }
      s += __shfl_xor(s, 16);
      s += __shfl_xor(s, 32);
      lrun[mi] += s;
    }

    // ---- P^T B-frag build (2-phase butterfly) + PV
    const int half = lq >> 1;
    const unsigned selp = (unsigned)((lq ^ half) & 1);
#pragma unroll
    for (int mi = 0; mi < 2; mi++) {
      bf16x8 pb[2];
#pragma unroll
      for (int win = 0; win < 2; win++) {
        unsigned u00, u01, u10, u11;   // u[kbw][pr]: keys 16*(2win+kbw)+4lq+{2pr,2pr+1}
        asm("v_cvt_pk_bf16_f32 %0, %1, %2" : "=v"(u00) : "v"(sf[mi][2*win][0]),   "v"(sf[mi][2*win][1]));
        asm("v_cvt_pk_bf16_f32 %0, %1, %2" : "=v"(u01) : "v"(sf[mi][2*win][2]),   "v"(sf[mi][2*win][3]));
        asm("v_cvt_pk_bf16_f32 %0, %1, %2" : "=v"(u10) : "v"(sf[mi][2*win+1][0]), "v"(sf[mi][2*win+1][1]));
        asm("v_cvt_pk_bf16_f32 %0, %1, %2" : "=v"(u11) : "v"(sf[mi][2*win+1][2]), "v"(sf[mi][2*win+1][3]));
        unsigned lw0 = half ? u10 : u00, lw1 = half ? u11 : u01;  // wanted kb, own group
        unsigned sa0 = half ? u00 : u10, sa1 = half ? u01 : u11;  // other kb -> phase 1
        unsigned y0 = (unsigned)__shfl_xor((int)sa0, 32);
        unsigned y1 = (unsigned)__shfl_xor((int)sa1, 32);
        unsigned z0 = selp ? lw0 : y0, z1 = selp ? lw1 : y1;      // phase 2 send
        unsigned r0 = (unsigned)__shfl_xor((int)z0, 16);
        unsigned r1 = (unsigned)__shfl_xor((int)z1, 16);
        unsigned wl0 = (lq == 0) ? lw0 : ((lq == 2) ? y0 : r0);
        unsigned wl1 = (lq == 0) ? lw1 : ((lq == 2) ? y1 : r1);
        unsigned wh0 = (lq == 3) ? lw0 : ((lq == 1) ? y0 : r0);
        unsigned wh1 = (lq == 3) ? lw1 : ((lq == 1) ? y1 : r1);
        union { unsigned u[4]; bf16x8 v; } pf;
        pf.u[0] = wl0; pf.u[1] = wl1; pf.u[2] = wh0; pf.u[3] = wh1;
        pb[win] = pf.v;
      }
#pragma unroll
      for (int db = 0; db < 4; db++) {
        oacc[mi][db] = __builtin_amdgcn_mfma_f32_16x16x32_bf16(va[db][0], pb[0], oacc[mi][db], 0, 0, 0);
        oacc[mi][db] = __builtin_amdgcn_mfma_f32_16x16x32_bf16(va[db][1], pb[1], oacc[mi][db], 0, 0, 0);
      }
    }
  };

  for (int kt = 0; kt < 2048; kt += 128) {
    tile(kaA, kaB, kt, kt + 64);
    tile(kaB, kaA, kt + 64, kt + 128);
  }

  // epilogue: O^T row = d = 16db + 4lq + r (verified C-layout), col q = l15
  const int b = bh >> 4, h = bh & 15;
#pragma unroll
  for (int mi = 0; mi < 2; mi++) {
    const float inv = 1.0f / lrun[mi];
    const int q = qbase + mi*16 + l15;
    const size_t base = ((size_t)b * 2048 + q) * 1024 + h * 64;
#pragma unroll
    for (int db = 0; db < 4; db++) {
      float e0 = oacc[mi][db][0] * inv, e1 = oacc[mi][db][1] * inv;
      float e2 = oacc[mi][db][2] * inv, e3 = oacc[mi][db][3] * inv;
      unsigned w0, w1;
      asm("v_cvt_pk_bf16_f32 %0, %1, %2" : "=v"(w0) : "v"(e0), "v"(e1));
      asm("v_cvt_pk_bf16_f32 %0, %1, %2" : "=v"(w1) : "v"(e2), "v"(e3));
      uint2 st; st.x = w0; st.y = w1;
      *(uint2*)(Ob + base + db*16 + lq*4) = st;
    }
  }
}

extern "C" void kernel_launch(void* const* d_in, const int* in_sizes, int n_in,
                              void* d_out, int out_size, void* d_ws, size_t ws_size,
                              hipStream_t stream) {
  const float* q  = (const float*)d_in[0];
  const float* k  = (const float*)d_in[1];
  const float* v  = (const float*)d_in[2];
  const float* Wq = (const float*)d_in[3];
  const float* bq = (const float*)d_in[4];
  const float* Wk = (const float*)d_in[5];
  const float* bk = (const float*)d_in[6];
  const float* Wv = (const float*)d_in[7];
  const float* bv = (const float*)d_in[8];
  const float* Wo = (const float*)d_in[9];
  const float* bo = (const float*)d_in[10];

  // ws: 4x bf16 weights (8MB) + Ob (16MB) + Qh/Kh/VT (48MB) = 72MB
  unsigned short* Wqb = (unsigned short*)d_ws;
  unsigned short* Wkb = Wqb + 1024 * 1024;
  unsigned short* Wvb = Wkb + 1024 * 1024;
  unsigned short* Wob = Wvb + 1024 * 1024;
  unsigned short* Ob  = Wob + 1024 * 1024;           // 8192*1024 bf16
  unsigned short* Qh  = Ob + (size_t)8192 * 1024;
  unsigned short* Kh  = Qh + (size_t)8192 * 1024;
  unsigned short* VT  = Kh + (size_t)8192 * 1024;

  const float QSCALE = 0.125f * 1.44269504f;  // 1/sqrt(64) * log2(e): exp2-space softmax

  cvt_kernel<<<1024, 256, 0, stream>>>(Wq, Wqb, 1024 * 1024);
  cvt_kernel<<<1024, 256, 0, stream>>>(Wk, Wkb, 1024 * 1024);
  cvt_kernel<<<1024, 256, 0, stream>>>(Wv, Wvb, 1024 * 1024);
  cvt_kernel<<<1024, 256, 0, stream>>>(Wo, Wob, 1024 * 1024);

  dim3 g(64, 8), blk(256);
  gemm_bt<true, 1><<<g, blk, 0, stream>>>(q, Wqb, bq, Qh, QSCALE);
  gemm_bt<true, 1><<<g, blk, 0, stream>>>(k, Wkb, bk, Kh, 1.0f);
  gemm_bt<true, 2><<<g, blk, 0, stream>>>(v, Wvb, bv, VT, 1.0f);

  attn_kernel<<<dim3(4096), dim3(64), 0, stream>>>(Qh, Kh, VT, Ob);

  gemm_bt<false, 0><<<g, blk, 0, stream>>>(Ob, Wob, bo, (float*)d_out, 1.0f);
}

// Round 10
// 522.045 us; speedup vs baseline: 1.4290x; 1.4290x over previous
//
#include <hip/hip_runtime.h>
#include <stdint.h>

#define DEVI __device__ __forceinline__

typedef __attribute__((ext_vector_type(8))) short bf16x8;   // MFMA A/B frag (8 bf16)
typedef __attribute__((ext_vector_type(4))) float f32x4;    // 16x16 MFMA C/D frag

DEVI unsigned short f2bf(float f) {  // fp32 -> bf16, round-to-nearest-even
  union { float f; unsigned u; } v; v.f = f;
  return (unsigned short)((v.u + 0x7FFFu + ((v.u >> 16) & 1u)) >> 16);
}

DEVI void gll16(const void* g, void* l) {  // global -> LDS direct, 16B/lane
  __builtin_amdgcn_global_load_lds((__attribute__((address_space(1))) void*)g,
                                   (__attribute__((address_space(3))) void*)l, 16, 0, 0);
}

// ---------------- fp32 -> bf16 conversion ----------------
__global__ __launch_bounds__(256) void cvt_kernel(const float* __restrict__ s,
                                                  unsigned short* __restrict__ d, int n) {
  int i = (blockIdx.x * 256 + threadIdx.x) * 4;
  if (i >= n) return;
  float4 v = *(const float4*)(s + i);
  union { unsigned short u[4]; uint2 w; } o;
  o.u[0] = f2bf(v.x); o.u[1] = f2bf(v.y); o.u[2] = f2bf(v.z); o.u[3] = f2bf(v.w);
  *(uint2*)(d + i) = o.w;
}

// ---------------- GEMM: C[M=8192,N=1024] = A(bf16) @ B(bf16)^T + bias ----------------
// Full m97 structure: BOTH operands via global_load_lds(16B) into linear [128][64] LDS
// (B-side pattern correctness-validated round 9: absmax bit-identical to reg-staged).
// OUT_MODE 0: fp32 row-major (val*oscale)
// OUT_MODE 1: bf16 heads [bh][s][64]
// OUT_MODE 2: bf16 headsT [bh][d][s]  (V^T for attention)
template<int OUT_MODE>
__global__ __launch_bounds__(256) void gemm_bt(const unsigned short* __restrict__ A,
                                               const unsigned short* __restrict__ B,
                                               const float* __restrict__ bias,
                                               void* __restrict__ Cptr, float oscale) {
  __shared__ __align__(16) unsigned short Al[128][64];
  __shared__ __align__(16) unsigned short Bl[128][64];
  const int tid = threadIdx.x, lane = tid & 63, w = tid >> 6;
  const int wm = w >> 1, wn = w & 1;            // 2x2 wave grid, 64x64 out per wave
  const int l15 = lane & 15, lq = lane >> 4;
  const int rowBase = blockIdx.x * 128, colBase = blockIdx.y * 128;

  f32x4 acc[4][4] = {};

  for (int k0 = 0; k0 < 1024; k0 += 64) {
    // stage both tiles direct-to-LDS: lane L -> row +(L>>3), col (L&7)*8 (linear dest)
#pragma unroll
    for (int i = 0; i < 4; i++) {
      int r = w * 32 + i * 8 + (lane >> 3);
      int c = k0 + (lane & 7) * 8;
      gll16(A + (size_t)(rowBase + r) * 1024 + c, &Al[w * 32 + i * 8][0]);
      gll16(B + (size_t)(colBase + r) * 1024 + c, &Bl[w * 32 + i * 8][0]);
    }
    __syncthreads();   // drains vmcnt -> LDS tiles ready
#pragma unroll
    for (int kc = 0; kc < 2; kc++) {
      bf16x8 af[4], bfr[4];
#pragma unroll
      for (int m = 0; m < 4; m++)
        af[m] = *(const bf16x8*)&Al[wm * 64 + m * 16 + l15][kc * 32 + lq * 8];
#pragma unroll
      for (int n = 0; n < 4; n++)
        bfr[n] = *(const bf16x8*)&Bl[wn * 64 + n * 16 + l15][kc * 32 + lq * 8];
#pragma unroll
      for (int m = 0; m < 4; m++)
#pragma unroll
        for (int n = 0; n < 4; n++)
          acc[m][n] = __builtin_amdgcn_mfma_f32_16x16x32_bf16(af[m], bfr[n], acc[m][n], 0, 0, 0);
    }
    __syncthreads();   // reads done before next tile overwrites
  }
  // epilogue: verified C/D layout col=lane&15, row=(lane>>4)*4+reg
#pragma unroll
  for (int n = 0; n < 4; n++) {
    int col = colBase + wn * 64 + n * 16 + l15;
    float bv = bias[col];
#pragma unroll
    for (int m = 0; m < 4; m++) {
      int row0 = rowBase + wm * 64 + m * 16 + lq * 4;
#pragma unroll
      for (int r = 0; r < 4; r++) {
        int row = row0 + r;
        float val = (acc[m][n][r] + bv) * oscale;
        if (OUT_MODE == 0) {
          ((float*)Cptr)[(size_t)row * 1024 + col] = val;
        } else {
          unsigned short* C = (unsigned short*)Cptr;
          int hh = col >> 6, dd = col & 63;
          int bb = row >> 11, ss = row & 2047;
          int bh = bb * 16 + hh;
          if (OUT_MODE == 1) C[(((size_t)bh * 2048 + ss) << 6) + dd] = f2bf(val);
          else               C[((size_t)bh << 17) + ((size_t)dd << 11) + ss] = f2bf(val);
        }
      }
    }
  }
}

// ---------------- flash attention: round-8 252us configuration, VERBATIM ----------------
// 1024 blocks x 4 independent waves (256 thr); zero LDS, zero barriers; VGPR 96 (no spill).
// S^T = mfma(K, Q^T): C col = q = l15, row = key(within 16-blk) = lq*4 + reg.
// Softmax in-register, exp2-space (Q pre-scaled by 0.125*log2e), defer-max THR=11.5.
__global__ __launch_bounds__(256, 2) void attn_kernel(const unsigned short* __restrict__ Qh,
                                                      const unsigned short* __restrict__ Kh,
                                                      const unsigned short* __restrict__ VT,
                                                      unsigned short* __restrict__ Ob) {
  const int tid = threadIdx.x, lane = tid & 63, w = tid >> 6;
  const int l15 = lane & 15, lq = lane >> 4;
  // XCD-chunked swizzle (1024 % 8 == 0, bijective): 8 bh (4MB K+V) per XCD L2
  const int bid = blockIdx.x;
  const int xcd = bid & 7, slot = bid >> 3;
  const int bh = xcd * 8 + (slot >> 4), qt = slot & 15;
  const int qbase = qt * 128 + w * 32;
  const unsigned short* Qp = Qh + ((size_t)bh << 17);
  const unsigned short* Kp = Kh + ((size_t)bh << 17);
  const unsigned short* Vp = VT + ((size_t)bh << 17);

  // Q B-frags: col=q=l15, k = kc*32 + lq*8 + j (verified round-0 convention)
  bf16x8 qb[2][2];
#pragma unroll
  for (int mi = 0; mi < 2; mi++)
#pragma unroll
    for (int kc = 0; kc < 2; kc++)
      qb[mi][kc] = *(const bf16x8*)(Qp + (size_t)(qbase + mi*16 + l15) * 64 + kc*32 + lq*8);

  f32x4 oacc[2][4] = {};                    // O^T: col=q=l15, row d = 16*db + 4*lq + reg
  float mrun[2] = {-1e30f, -1e30f};
  float lrun[2] = {0.f, 0.f};

  bf16x8 kaA[4][2], kaB[4][2];              // K A-frags, double-buffered
  auto loadK = [&](bf16x8 (&ka)[4][2], int kt) {
#pragma unroll
    for (int kb = 0; kb < 4; kb++)
#pragma unroll
      for (int kc = 0; kc < 2; kc++)
        ka[kb][kc] = *(const bf16x8*)(Kp + (size_t)(kt + kb*16 + l15) * 64 + kc*32 + lq*8);
  };
  loadK(kaA, 0);

  auto tile = [&](bf16x8 (&ka)[4][2], bf16x8 (&kan)[4][2], int kt, int ktn) {
    // V^T A-frags: row d = db*16 + l15, k = key = win*32 + lq*8 + j
    bf16x8 va[4][2];
#pragma unroll
    for (int db = 0; db < 4; db++)
#pragma unroll
      for (int win = 0; win < 2; win++)
        va[db][win] = *(const bf16x8*)(Vp + (size_t)(db*16 + l15) * 2048 + kt + win*32 + lq*8);

    // QK^T: sf[mi][kb][r] = score(q = qbase+16mi+l15, key = kt+16kb+4lq+r), log2-scaled
    f32x4 sf[2][4] = {};
#pragma unroll
    for (int kc = 0; kc < 2; kc++)
#pragma unroll
      for (int mi = 0; mi < 2; mi++)
#pragma unroll
        for (int kb = 0; kb < 4; kb++)
          sf[mi][kb] = __builtin_amdgcn_mfma_f32_16x16x32_bf16(ka[kb][kc], qb[mi][kc], sf[mi][kb], 0, 0, 0);

    if (ktn < 2048) loadK(kan, ktn);       // prefetch next K under softmax

    // ---- online softmax: local 16-tree + shfl_xor{16,32} across the 4 lq-groups
    float pm[2];
#pragma unroll
    for (int mi = 0; mi < 2; mi++) {
      float t0 = fmaxf(fmaxf(sf[mi][0][0], sf[mi][0][1]), fmaxf(sf[mi][0][2], sf[mi][0][3]));
      float t1 = fmaxf(fmaxf(sf[mi][1][0], sf[mi][1][1]), fmaxf(sf[mi][1][2], sf[mi][1][3]));
      float t2 = fmaxf(fmaxf(sf[mi][2][0], sf[mi][2][1]), fmaxf(sf[mi][2][2], sf[mi][2][3]));
      float t3 = fmaxf(fmaxf(sf[mi][3][0], sf[mi][3][1]), fmaxf(sf[mi][3][2], sf[mi][3][3]));
      float t = fmaxf(fmaxf(t0, t1), fmaxf(t2, t3));
      t = fmaxf(t, __shfl_xor(t, 16));
      t = fmaxf(t, __shfl_xor(t, 32));
      pm[mi] = t;
    }
    if (__any((pm[0] > mrun[0] + 11.5f) || (pm[1] > mrun[1] + 11.5f))) {  // defer-max
#pragma unroll
      for (int mi = 0; mi < 2; mi++) {
        float mnew = fmaxf(mrun[mi], pm[mi]);
        float alpha = __builtin_amdgcn_exp2f(mrun[mi] - mnew);
        mrun[mi] = mnew; lrun[mi] *= alpha;
#pragma unroll
        for (int db = 0; db < 4; db++)
#pragma unroll
          for (int r = 0; r < 4; r++) oacc[mi][db][r] *= alpha;
      }
    }
#pragma unroll
    for (int mi = 0; mi < 2; mi++) {
      float s = 0.f;
#pragma unroll
      for (int kb = 0; kb < 4; kb++)
#pragma unroll
        for (int r = 0; r < 4; r++) {
          float e = __builtin_amdgcn_exp2f(sf[mi][kb][r] - mrun[mi]);
          sf[mi][kb][r] = e; s += e;
        }
      s += __shfl_xor(s, 16);
      s += __shfl_xor(s, 32);
      lrun[mi] += s;
    }

    // ---- P^T B-frag build (2-phase butterfly) + PV
    const int half = lq >> 1;
    const unsigned selp = (unsigned)((lq ^ half) & 1);
#pragma unroll
    for (int mi = 0; mi < 2; mi++) {
      bf16x8 pb[2];
#pragma unroll
      for (int win = 0; win < 2; win++) {
        unsigned u00, u01, u10, u11;   // u[kbw][pr]: keys 16*(2win+kbw)+4lq+{2pr,2pr+1}
        asm("v_cvt_pk_bf16_f32 %0, %1, %2" : "=v"(u00) : "v"(sf[mi][2*win][0]),   "v"(sf[mi][2*win][1]));
        asm("v_cvt_pk_bf16_f32 %0, %1, %2" : "=v"(u01) : "v"(sf[mi][2*win][2]),   "v"(sf[mi][2*win][3]));
        asm("v_cvt_pk_bf16_f32 %0, %1, %2" : "=v"(u10) : "v"(sf[mi][2*win+1][0]), "v"(sf[mi][2*win+1][1]));
        asm("v_cvt_pk_bf16_f32 %0, %1, %2" : "=v"(u11) : "v"(sf[mi][2*win+1][2]), "v"(sf[mi][2*win+1][3]));
        unsigned lw0 = half ? u10 : u00, lw1 = half ? u11 : u01;  // wanted kb, own group
        unsigned sa0 = half ? u00 : u10, sa1 = half ? u01 : u11;  // other kb -> phase 1
        unsigned y0 = (unsigned)__shfl_xor((int)sa0, 32);
        unsigned y1 = (unsigned)__shfl_xor((int)sa1, 32);
        unsigned z0 = selp ? lw0 : y0, z1 = selp ? lw1 : y1;      // phase 2 send
        unsigned r0 = (unsigned)__shfl_xor((int)z0, 16);
        unsigned r1 = (unsigned)__shfl_xor((int)z1, 16);
        unsigned wl0 = (lq == 0) ? lw0 : ((lq == 2) ? y0 : r0);
        unsigned wl1 = (lq == 0) ? lw1 : ((lq == 2) ? y1 : r1);
        unsigned wh0 = (lq == 3) ? lw0 : ((lq == 1) ? y0 : r0);
        unsigned wh1 = (lq == 3) ? lw1 : ((lq == 1) ? y1 : r1);
        union { unsigned u[4]; bf16x8 v; } pf;
        pf.u[0] = wl0; pf.u[1] = wl1; pf.u[2] = wh0; pf.u[3] = wh1;
        pb[win] = pf.v;
      }
#pragma unroll
      for (int db = 0; db < 4; db++) {
        oacc[mi][db] = __builtin_amdgcn_mfma_f32_16x16x32_bf16(va[db][0], pb[0], oacc[mi][db], 0, 0, 0);
        oacc[mi][db] = __builtin_amdgcn_mfma_f32_16x16x32_bf16(va[db][1], pb[1], oacc[mi][db], 0, 0, 0);
      }
    }
  };

  for (int kt = 0; kt < 2048; kt += 128) {
    tile(kaA, kaB, kt, kt + 64);
    tile(kaB, kaA, kt + 64, kt + 128);
  }

  // epilogue: O^T row = d = 16db + 4lq + r (verified C-layout), col q = l15
  const int b = bh >> 4, h = bh & 15;
#pragma unroll
  for (int mi = 0; mi < 2; mi++) {
    const float inv = 1.0f / lrun[mi];
    const int q = qbase + mi*16 + l15;
    const size_t base = ((size_t)b * 2048 + q) * 1024 + h * 64;
#pragma unroll
    for (int db = 0; db < 4; db++) {
      float e0 = oacc[mi][db][0] * inv, e1 = oacc[mi][db][1] * inv;
      float e2 = oacc[mi][db][2] * inv, e3 = oacc[mi][db][3] * inv;
      unsigned w0, w1;
      asm("v_cvt_pk_bf16_f32 %0, %1, %2" : "=v"(w0) : "v"(e0), "v"(e1));
      asm("v_cvt_pk_bf16_f32 %0, %1, %2" : "=v"(w1) : "v"(e2), "v"(e3));
      uint2 st; st.x = w0; st.y = w1;
      *(uint2*)(Ob + base + db*16 + lq*4) = st;
    }
  }
}

extern "C" void kernel_launch(void* const* d_in, const int* in_sizes, int n_in,
                              void* d_out, int out_size, void* d_ws, size_t ws_size,
                              hipStream_t stream) {
  const float* q  = (const float*)d_in[0];
  const float* k  = (const float*)d_in[1];
  const float* v  = (const float*)d_in[2];
  const float* Wq = (const float*)d_in[3];
  const float* bq = (const float*)d_in[4];
  const float* Wk = (const float*)d_in[5];
  const float* bk = (const float*)d_in[6];
  const float* Wv = (const float*)d_in[7];
  const float* bv = (const float*)d_in[8];
  const float* Wo = (const float*)d_in[9];
  const float* bo = (const float*)d_in[10];

  // ws (72MB): 4x bf16 weights (8MB) + Xbf/Ob shared 16MB (input-bf16, then attn-out)
  //          + Qh/Kh/VT (48MB)
  unsigned short* Wqb = (unsigned short*)d_ws;
  unsigned short* Wkb = Wqb + 1024 * 1024;
  unsigned short* Wvb = Wkb + 1024 * 1024;
  unsigned short* Wvb2= Wvb;  // silence unused warnings pattern-free
  unsigned short* Wob = Wvb + 1024 * 1024;
  unsigned short* Xbf = Wob + 1024 * 1024;           // 8192*1024 bf16
  unsigned short* Qh  = Xbf + (size_t)8192 * 1024;
  unsigned short* Kh  = Qh + (size_t)8192 * 1024;
  unsigned short* VT  = Kh + (size_t)8192 * 1024;
  unsigned short* Ob  = Xbf;                          // alias: Xbf dead after V-proj
  (void)Wvb2;

  const float QSCALE = 0.125f * 1.44269504f;  // 1/sqrt(64) * log2(e): exp2-space softmax

  cvt_kernel<<<1024, 256, 0, stream>>>(Wq, Wqb, 1024 * 1024);
  cvt_kernel<<<1024, 256, 0, stream>>>(Wk, Wkb, 1024 * 1024);
  cvt_kernel<<<1024, 256, 0, stream>>>(Wv, Wvb, 1024 * 1024);
  cvt_kernel<<<1024, 256, 0, stream>>>(Wo, Wob, 1024 * 1024);

  dim3 g(64, 8), blk(256);
  cvt_kernel<<<8192, 256, 0, stream>>>(q, Xbf, 8192 * 1024);
  gemm_bt<1><<<g, blk, 0, stream>>>(Xbf, Wqb, bq, Qh, QSCALE);
  cvt_kernel<<<8192, 256, 0, stream>>>(k, Xbf, 8192 * 1024);
  gemm_bt<1><<<g, blk, 0, stream>>>(Xbf, Wkb, bk, Kh, 1.0f);
  cvt_kernel<<<8192, 256, 0, stream>>>(v, Xbf, 8192 * 1024);
  gemm_bt<2><<<g, blk, 0, stream>>>(Xbf, Wvb, bv, VT, 1.0f);

  attn_kernel<<<dim3(1024), blk, 0, stream>>>(Qh, Kh, VT, Ob);

  gemm_bt<0><<<g, blk, 0, stream>>>(Ob, Wob, bo, (float*)d_out, 1.0f);
}